// Round 1
// baseline (233.794 us; speedup 1.0000x reference)
//
#include <hip/hip_runtime.h>
#include <hip/hip_bf16.h>

#define TFULL 4096
#define NBATCH 8
#define INDIM 128
#define OUTDIM 128
#define HIDDIM 256
#define LCH 64
#define NCH (TFULL / LCH)   // 64

static __device__ __forceinline__ unsigned short f2bf(float f) {
    unsigned int x = __float_as_uint(f);
    x += 0x7fffu + ((x >> 16) & 1u);   // round-to-nearest-even
    return (unsigned short)(x >> 16);
}

// ---------------------------------------------------------------------------
// K1: BX = X @ (gamma*B)^T for one (batch, 64-t chunk, 128-h half), then
//     sequential local scan over the 64 steps; h_local stored bf16x2, chunk
//     end state E stored fp32.
// ---------------------------------------------------------------------------
__global__ __launch_bounds__(256) void k_bx_scan(
    const float* __restrict__ X, const float* __restrict__ nu_log,
    const float* __restrict__ theta_log, const float* __restrict__ B_re,
    const float* __restrict__ B_im, unsigned int* __restrict__ hloc,
    float2* __restrict__ E)
{
    __shared__ float smem[17024];
    float*  XT  = smem;            // [128][68] X^T (i-major)
    float*  Brl = smem + 8704;     // [32][130]
    float*  Bil = smem + 12864;    // [32][130]
    float2* sb  = (float2*)smem;   // scan buffer [64][130], aliases above

    const int tid = threadIdx.x;
    const int blk = blockIdx.x;
    const int b   = blk >> 7;
    const int c   = (blk >> 1) & 63;
    const int h0  = (blk & 1) * 128;
    const int t0  = c * LCH;

    // ---- stage X^T: rows t0..t0+63, all 128 i ----
    {
        const float* Xb = X + ((size_t)(b * TFULL + t0)) * INDIM;
        int r = tid >> 2;          // t row 0..63
        int q = tid & 3;
        #pragma unroll
        for (int k = 0; k < 8; ++k) {
            int slot = q + k * 4;  // float4 col 0..31
            float4 v = *(const float4*)(Xb + (size_t)r * INDIM + slot * 4);
            float* dst = XT + (slot * 4) * 68 + r;
            dst[0]      = v.x;
            dst[68]     = v.y;
            dst[2 * 68] = v.z;
            dst[3 * 68] = v.w;
        }
    }

    float accre[8][4], accim[8][4];
    #pragma unroll
    for (int r = 0; r < 8; ++r)
        #pragma unroll
        for (int j = 0; j < 4; ++j) { accre[r][j] = 0.f; accim[r][j] = 0.f; }

    const int ty = tid >> 5;   // 0..7  (t group)
    const int tx = tid & 31;   // 0..31 (h group)

    for (int kc = 0; kc < 4; ++kc) {
        __syncthreads();
        // ---- stage gamma-scaled B chunk (cols kc*32..+31, rows h0..h0+127) ----
        {
            int hr = tid >> 1;     // 0..127
            int s  = tid & 1;
            int hg = h0 + hr;
            float mag = expf(-expf(nu_log[hg]));
            float gam = sqrtf(fmaxf(0.f, 1.f - mag * mag));
            const float* br = B_re + (size_t)hg * INDIM + kc * 32;
            const float* bi = B_im + (size_t)hg * INDIM + kc * 32;
            #pragma unroll
            for (int q = 0; q < 4; ++q) {
                int col = s * 16 + q * 4;
                float4 vr = *(const float4*)(br + col);
                float4 vi = *(const float4*)(bi + col);
                Brl[(col + 0) * 130 + hr] = vr.x * gam;
                Brl[(col + 1) * 130 + hr] = vr.y * gam;
                Brl[(col + 2) * 130 + hr] = vr.z * gam;
                Brl[(col + 3) * 130 + hr] = vr.w * gam;
                Bil[(col + 0) * 130 + hr] = vi.x * gam;
                Bil[(col + 1) * 130 + hr] = vi.y * gam;
                Bil[(col + 2) * 130 + hr] = vi.z * gam;
                Bil[(col + 3) * 130 + hr] = vi.w * gam;
            }
        }
        __syncthreads();
        for (int kk = 0; kk < 32; ++kk) {
            const float* xrow = XT + (kc * 32 + kk) * 68 + ty * 8;
            float4 xa = *(const float4*)(xrow);
            float4 xb = *(const float4*)(xrow + 4);
            float2 br0 = *(const float2*)(Brl + kk * 130 + 2 * tx);
            float2 br1 = *(const float2*)(Brl + kk * 130 + 64 + 2 * tx);
            float2 bi0 = *(const float2*)(Bil + kk * 130 + 2 * tx);
            float2 bi1 = *(const float2*)(Bil + kk * 130 + 64 + 2 * tx);
            float xs[8]  = {xa.x, xa.y, xa.z, xa.w, xb.x, xb.y, xb.z, xb.w};
            float brs[4] = {br0.x, br0.y, br1.x, br1.y};
            float bis[4] = {bi0.x, bi0.y, bi1.x, bi1.y};
            #pragma unroll
            for (int r = 0; r < 8; ++r)
                #pragma unroll
                for (int j = 0; j < 4; ++j) {
                    accre[r][j] = fmaf(xs[r], brs[j], accre[r][j]);
                    accim[r][j] = fmaf(xs[r], bis[j], accim[r][j]);
                }
        }
    }

    __syncthreads();
    // ---- dump BX tile to LDS (canonical h index) ----
    #pragma unroll
    for (int r = 0; r < 8; ++r) {
        int t = ty * 8 + r;
        #pragma unroll
        for (int j = 0; j < 4; ++j) {
            int hl = (j < 2) ? (2 * tx + j) : (64 + 2 * tx + (j - 2));
            sb[t * 130 + hl] = make_float2(accre[r][j], accim[r][j]);
        }
    }
    __syncthreads();

    // ---- sequential complex scan over 64 steps, threads 0..127 = h ----
    if (tid < 128) {
        int hl = tid, hg = h0 + hl;
        float nu = expf(nu_log[hg]), th = expf(theta_log[hg]);
        float mag = expf(-nu);
        float lre = mag * cosf(th), lim = mag * sinf(th);
        float sre = 0.f, sim = 0.f;
        unsigned int* hout = hloc + (size_t)(b * TFULL + t0) * HIDDIM + h0 + hl;
        for (int t = 0; t < LCH; ++t) {
            float2 v = sb[t * 130 + hl];
            float nre = fmaf(lre, sre, fmaf(-lim, sim, v.x));
            float nim = fmaf(lre, sim, fmaf(lim, sre, v.y));
            sre = nre; sim = nim;
            hout[(size_t)t * HIDDIM] =
                ((unsigned int)f2bf(sim) << 16) | (unsigned int)f2bf(sre);
        }
        E[((size_t)b * NCH + c) * HIDDIM + h0 + hl] = make_float2(sre, sim);
    }
}

// ---------------------------------------------------------------------------
// K2: carries across chunks (lam^64 closed form) + lam^(t+1) table.
// ---------------------------------------------------------------------------
__global__ __launch_bounds__(256) void k_carry(
    const float* __restrict__ nu_log, const float* __restrict__ theta_log,
    const float2* __restrict__ E, float2* __restrict__ Carr,
    float2* __restrict__ lampow)
{
    int blk = blockIdx.x, tid = threadIdx.x;
    if (blk < NBATCH) {
        int b = blk, h = tid;
        float nu = expf(nu_log[h]), th = expf(theta_log[h]);
        float m = expf(-(float)LCH * nu);
        float Lre = m * cosf((float)LCH * th);
        float Lim = m * sinf((float)LCH * th);
        float cre = 0.f, cim = 0.f;
        for (int c = 0; c < NCH; ++c) {
            size_t idx = ((size_t)b * NCH + c) * HIDDIM + h;
            Carr[idx] = make_float2(cre, cim);
            float2 e = E[idx];
            float nre = e.x + Lre * cre - Lim * cim;
            float nim = e.y + Lre * cim + Lim * cre;
            cre = nre; cim = nim;
        }
    } else {
        int idx = (blk - NBATCH) * 256 + tid;   // 0..16383
        int tl = idx >> 8;
        int h  = idx & 255;
        float nu = expf(nu_log[h]), th = expf(theta_log[h]);
        float k = (float)(tl + 1);
        float m = expf(-k * nu);
        lampow[idx] = make_float2(m * cosf(k * th), m * sinf(k * th));
    }
}

// ---------------------------------------------------------------------------
// K3: Y = Re((h_local + lam^(t+1)*carry) @ Cc^T) + X @ D^T for one (b, chunk).
// ---------------------------------------------------------------------------
__global__ __launch_bounds__(256) void k_y(
    const float* __restrict__ X, const unsigned int* __restrict__ hloc,
    const float2* __restrict__ Carr, const float2* __restrict__ lampow,
    const float* __restrict__ C_re, const float* __restrict__ C_im,
    const float* __restrict__ D, float* __restrict__ Y)
{
    __shared__ float smem[12800];
    float* hreT = smem;           // [32][68]
    float* himT = smem + 2176;    // [32][68]
    float* CreT = smem + 4352;    // [32][132]
    float* CimT = smem + 8576;    // [32][132]
    float* XT   = smem;           // phase-B alias [32][68]
    float* DT   = smem + 4352;    // phase-B alias [32][132]

    int tid = threadIdx.x;
    int b = blockIdx.x >> 6, c = blockIdx.x & 63;
    int t0 = c * LCH;
    int ty = tid >> 5, tx = tid & 31;

    float y[8][4];
    #pragma unroll
    for (int r = 0; r < 8; ++r)
        #pragma unroll
        for (int j = 0; j < 4; ++j) y[r][j] = 0.f;

    // ---- C term: K = 256 h in 8 chunks of 32 ----
    for (int kc = 0; kc < 8; ++kc) {
        int k0 = kc * 32;
        __syncthreads();
        #pragma unroll
        for (int k = 0; k < 8; ++k) {
            int idx = k * 256 + tid;
            int t = idx >> 5, kk = idx & 31;
            unsigned int u = hloc[((size_t)(b * TFULL) + t0 + t) * HIDDIM + k0 + kk];
            float2 lp = lampow[t * HIDDIM + k0 + kk];
            float2 cr = Carr[((size_t)b * NCH + c) * HIDDIM + k0 + kk];
            float hre = __uint_as_float(u << 16) + lp.x * cr.x - lp.y * cr.y;
            float him = __uint_as_float(u & 0xffff0000u) + lp.x * cr.y + lp.y * cr.x;
            hreT[kk * 68 + t] = hre;
            himT[kk * 68 + t] = him;
        }
        #pragma unroll
        for (int k = 0; k < 4; ++k) {
            int idx4 = k * 256 + tid;        // 0..1023
            int o = idx4 >> 3, q = idx4 & 7;
            float4 vr = *(const float4*)(C_re + (size_t)o * HIDDIM + k0 + q * 4);
            float4 vi = *(const float4*)(C_im + (size_t)o * HIDDIM + k0 + q * 4);
            CreT[(q * 4 + 0) * 132 + o] = vr.x;
            CreT[(q * 4 + 1) * 132 + o] = vr.y;
            CreT[(q * 4 + 2) * 132 + o] = vr.z;
            CreT[(q * 4 + 3) * 132 + o] = vr.w;
            CimT[(q * 4 + 0) * 132 + o] = vi.x;
            CimT[(q * 4 + 1) * 132 + o] = vi.y;
            CimT[(q * 4 + 2) * 132 + o] = vi.z;
            CimT[(q * 4 + 3) * 132 + o] = vi.w;
        }
        __syncthreads();
        for (int kk = 0; kk < 32; ++kk) {
            const float* hr = hreT + kk * 68 + ty * 8;
            const float* hi = himT + kk * 68 + ty * 8;
            float4 ara = *(const float4*)(hr), arb = *(const float4*)(hr + 4);
            float4 aia = *(const float4*)(hi), aib = *(const float4*)(hi + 4);
            float2 cr0 = *(const float2*)(CreT + kk * 132 + 2 * tx);
            float2 cr1 = *(const float2*)(CreT + kk * 132 + 64 + 2 * tx);
            float2 ci0 = *(const float2*)(CimT + kk * 132 + 2 * tx);
            float2 ci1 = *(const float2*)(CimT + kk * 132 + 64 + 2 * tx);
            float ar[8] = {ara.x, ara.y, ara.z, ara.w, arb.x, arb.y, arb.z, arb.w};
            float ai[8] = {aia.x, aia.y, aia.z, aia.w, aib.x, aib.y, aib.z, aib.w};
            float crs[4] = {cr0.x, cr0.y, cr1.x, cr1.y};
            float cis[4] = {ci0.x, ci0.y, ci1.x, ci1.y};
            #pragma unroll
            for (int r = 0; r < 8; ++r)
                #pragma unroll
                for (int j = 0; j < 4; ++j) {
                    y[r][j] = fmaf(ar[r], crs[j], y[r][j]);
                    y[r][j] = fmaf(-ai[r], cis[j], y[r][j]);
                }
        }
    }

    // ---- D term: K = 128 i in 4 chunks of 32 ----
    for (int ic = 0; ic < 4; ++ic) {
        int i0 = ic * 32;
        __syncthreads();
        #pragma unroll
        for (int k = 0; k < 8; ++k) {
            int idx = k * 256 + tid;
            int t = idx >> 5, kk = idx & 31;
            XT[kk * 68 + t] = X[((size_t)(b * TFULL) + t0 + t) * INDIM + i0 + kk];
        }
        #pragma unroll
        for (int k = 0; k < 4; ++k) {
            int idx4 = k * 256 + tid;
            int o = idx4 >> 3, q = idx4 & 7;
            float4 v = *(const float4*)(D + (size_t)o * INDIM + i0 + q * 4);
            DT[(q * 4 + 0) * 132 + o] = v.x;
            DT[(q * 4 + 1) * 132 + o] = v.y;
            DT[(q * 4 + 2) * 132 + o] = v.z;
            DT[(q * 4 + 3) * 132 + o] = v.w;
        }
        __syncthreads();
        for (int kk = 0; kk < 32; ++kk) {
            const float* xr = XT + kk * 68 + ty * 8;
            float4 xa = *(const float4*)(xr), xb = *(const float4*)(xr + 4);
            float2 d0 = *(const float2*)(DT + kk * 132 + 2 * tx);
            float2 d1 = *(const float2*)(DT + kk * 132 + 64 + 2 * tx);
            float xs[8] = {xa.x, xa.y, xa.z, xa.w, xb.x, xb.y, xb.z, xb.w};
            float ds[4] = {d0.x, d0.y, d1.x, d1.y};
            #pragma unroll
            for (int r = 0; r < 8; ++r)
                #pragma unroll
                for (int j = 0; j < 4; ++j)
                    y[r][j] = fmaf(xs[r], ds[j], y[r][j]);
        }
    }

    // ---- store Y (o-pair mapping {2tx,2tx+1} and {64+2tx,65+2tx}) ----
    float* Yb = Y + ((size_t)(b * TFULL) + t0) * OUTDIM;
    #pragma unroll
    for (int r = 0; r < 8; ++r) {
        int t = ty * 8 + r;
        *(float2*)(Yb + (size_t)t * OUTDIM + 2 * tx)      = make_float2(y[r][0], y[r][1]);
        *(float2*)(Yb + (size_t)t * OUTDIM + 64 + 2 * tx) = make_float2(y[r][2], y[r][3]);
    }
}

// ---------------------------------------------------------------------------
extern "C" void kernel_launch(void* const* d_in, const int* in_sizes, int n_in,
                              void* d_out, int out_size, void* d_ws, size_t ws_size,
                              hipStream_t stream) {
    const float* X         = (const float*)d_in[0];
    const float* nu_log    = (const float*)d_in[1];
    const float* theta_log = (const float*)d_in[2];
    const float* B_re      = (const float*)d_in[3];
    const float* B_im      = (const float*)d_in[4];
    const float* C_re      = (const float*)d_in[5];
    const float* C_im      = (const float*)d_in[6];
    const float* D         = (const float*)d_in[7];
    float* Y = (float*)d_out;

    // workspace layout (34.1 MB total)
    unsigned int* hloc = (unsigned int*)d_ws;                              // 8*4096*256 u32 = 32 MB
    float2* E      = (float2*)((char*)d_ws + (size_t)33554432);            // 8*64*256 float2 = 1 MB
    float2* Carr   = (float2*)((char*)d_ws + (size_t)34603008);            // 1 MB
    float2* lampow = (float2*)((char*)d_ws + (size_t)35651584);            // 64*256 float2 = 128 KB

    hipLaunchKernelGGL(k_bx_scan, dim3(NBATCH * NCH * 2), dim3(256), 0, stream,
                       X, nu_log, theta_log, B_re, B_im, hloc, E);
    hipLaunchKernelGGL(k_carry, dim3(NBATCH + 64), dim3(256), 0, stream,
                       nu_log, theta_log, E, Carr, lampow);
    hipLaunchKernelGGL(k_y, dim3(NBATCH * NCH), dim3(256), 0, stream,
                       X, hloc, Carr, lampow, C_re, C_im, D, Y);
}

// Round 5
// 174.766 us; speedup vs baseline: 1.3378x; 1.3378x over previous
//
#include <hip/hip_runtime.h>
#include <hip/hip_bf16.h>

#define TFULL 4096
#define NBATCH 8
#define INDIM 128
#define OUTDIM 128
#define HIDDIM 256
#define LCH 64
#define NCH (TFULL / LCH)   // 64

typedef float f32x4 __attribute__((ext_vector_type(4)));
typedef short short8 __attribute__((ext_vector_type(8)));

static __device__ __forceinline__ unsigned short f2bf(float f) {
    unsigned int x = __float_as_uint(f);
    x += 0x7fffu + ((x >> 16) & 1u);   // round-to-nearest-even
    return (unsigned short)(x >> 16);
}
static __device__ __forceinline__ unsigned int pack2(float a, float b) {
    return ((unsigned int)f2bf(b) << 16) | (unsigned int)f2bf(a);
}
static __device__ __forceinline__ float bflo(unsigned int u) {
    return __uint_as_float(u << 16);
}
static __device__ __forceinline__ float bfhi(unsigned int u) {
    return __uint_as_float(u & 0xffff0000u);
}
// split fp32 into hi/lo bf16 pair (v ~= hi + lo to ~16.5 mantissa bits)
static __device__ __forceinline__ void split2(float v, unsigned short& hi, unsigned short& lo) {
    hi = f2bf(v);
    lo = f2bf(v - __uint_as_float((unsigned int)hi << 16));
}

// ---------------------------------------------------------------------------
// K0: precompute hi/lo bf16 output-GEMM weights + lam^(t+1) table.
//  Wy [kc=10][o=128][kk=64] : k=64*kc+kk; k<512: (k&1? -C_im : C_re)[o][k>>1]
//     else D[o][k-512]
//  lampow [64][256] float2 = lam^(tl+1)
// ---------------------------------------------------------------------------
__global__ __launch_bounds__(256) void k_prep(
    const float* __restrict__ nu_log, const float* __restrict__ theta_log,
    const float* __restrict__ C_re, const float* __restrict__ C_im,
    const float* __restrict__ D,
    unsigned short* __restrict__ Wy_hi, unsigned short* __restrict__ Wy_lo,
    float2* __restrict__ lampow)
{
    int f = blockIdx.x * 256 + threadIdx.x;   // grid 384 -> f < 98304
    if (f < 81920) {
        int q = f;
        int kk = q & 63, o = (q >> 6) & 127, kc = q >> 13;
        int k = 64 * kc + kk;
        float v;
        if (k < 512) {
            int h = k >> 1;
            v = (k & 1) ? -C_im[o * HIDDIM + h] : C_re[o * HIDDIM + h];
        } else {
            v = D[o * INDIM + (k - 512)];
        }
        unsigned short hi, lo; split2(v, hi, lo);
        Wy_hi[q] = hi; Wy_lo[q] = lo;
    } else {
        int l = f - 81920;                    // [0, 16384)
        int h = l & 255, tl = l >> 8;
        float nu = expf(nu_log[h]), th = expf(theta_log[h]);
        float kf = (float)(tl + 1);
        float m = expf(-kf * nu);
        lampow[l] = make_float2(m * cosf(kf * th), m * sinf(kf * th));
    }
}

// ---------------------------------------------------------------------------
// K1 (PROVEN round-1 kernel, verbatim): fp32 VALU GEMM BX for one
// (batch, 64-t chunk, 128-h half) + sequential local scan; hloc bf16x2,
// chunk-end E fp32 into EC.
// ---------------------------------------------------------------------------
__global__ __launch_bounds__(256) void k_bx_scan(
    const float* __restrict__ X, const float* __restrict__ nu_log,
    const float* __restrict__ theta_log, const float* __restrict__ B_re,
    const float* __restrict__ B_im, unsigned int* __restrict__ hloc,
    float2* __restrict__ EC)
{
    __shared__ float smem[17024];
    float*  XT  = smem;            // [128][68] X^T (i-major)
    float*  Brl = smem + 8704;     // [32][130]
    float*  Bil = smem + 12864;    // [32][130]
    float2* sb  = (float2*)smem;   // scan buffer [64][130], aliases above

    const int tid = threadIdx.x;
    const int blk = blockIdx.x;
    const int b   = blk >> 7;
    const int c   = (blk >> 1) & 63;
    const int h0  = (blk & 1) * 128;
    const int t0  = c * LCH;

    // ---- stage X^T: rows t0..t0+63, all 128 i ----
    {
        const float* Xb = X + ((size_t)(b * TFULL + t0)) * INDIM;
        int r = tid >> 2;          // t row 0..63
        int q = tid & 3;
        #pragma unroll
        for (int k = 0; k < 8; ++k) {
            int slot = q + k * 4;  // float4 col 0..31
            float4 v = *(const float4*)(Xb + (size_t)r * INDIM + slot * 4);
            float* dst = XT + (slot * 4) * 68 + r;
            dst[0]      = v.x;
            dst[68]     = v.y;
            dst[2 * 68] = v.z;
            dst[3 * 68] = v.w;
        }
    }

    float accre[8][4], accim[8][4];
    #pragma unroll
    for (int r = 0; r < 8; ++r)
        #pragma unroll
        for (int j = 0; j < 4; ++j) { accre[r][j] = 0.f; accim[r][j] = 0.f; }

    const int ty = tid >> 5;   // 0..7  (t group)
    const int tx = tid & 31;   // 0..31 (h group)

    for (int kc = 0; kc < 4; ++kc) {
        __syncthreads();
        // ---- stage gamma-scaled B chunk (cols kc*32..+31, rows h0..h0+127) ----
        {
            int hr = tid >> 1;     // 0..127
            int s  = tid & 1;
            int hg = h0 + hr;
            float mag = expf(-expf(nu_log[hg]));
            float gam = sqrtf(fmaxf(0.f, 1.f - mag * mag));
            const float* br = B_re + (size_t)hg * INDIM + kc * 32;
            const float* bi = B_im + (size_t)hg * INDIM + kc * 32;
            #pragma unroll
            for (int q = 0; q < 4; ++q) {
                int col = s * 16 + q * 4;
                float4 vr = *(const float4*)(br + col);
                float4 vi = *(const float4*)(bi + col);
                Brl[(col + 0) * 130 + hr] = vr.x * gam;
                Brl[(col + 1) * 130 + hr] = vr.y * gam;
                Brl[(col + 2) * 130 + hr] = vr.z * gam;
                Brl[(col + 3) * 130 + hr] = vr.w * gam;
                Bil[(col + 0) * 130 + hr] = vi.x * gam;
                Bil[(col + 1) * 130 + hr] = vi.y * gam;
                Bil[(col + 2) * 130 + hr] = vi.z * gam;
                Bil[(col + 3) * 130 + hr] = vi.w * gam;
            }
        }
        __syncthreads();
        for (int kk = 0; kk < 32; ++kk) {
            const float* xrow = XT + (kc * 32 + kk) * 68 + ty * 8;
            float4 xa = *(const float4*)(xrow);
            float4 xb = *(const float4*)(xrow + 4);
            float2 br0 = *(const float2*)(Brl + kk * 130 + 2 * tx);
            float2 br1 = *(const float2*)(Brl + kk * 130 + 64 + 2 * tx);
            float2 bi0 = *(const float2*)(Bil + kk * 130 + 2 * tx);
            float2 bi1 = *(const float2*)(Bil + kk * 130 + 64 + 2 * tx);
            float xs[8]  = {xa.x, xa.y, xa.z, xa.w, xb.x, xb.y, xb.z, xb.w};
            float brs[4] = {br0.x, br0.y, br1.x, br1.y};
            float bis[4] = {bi0.x, bi0.y, bi1.x, bi1.y};
            #pragma unroll
            for (int r = 0; r < 8; ++r)
                #pragma unroll
                for (int j = 0; j < 4; ++j) {
                    accre[r][j] = fmaf(xs[r], brs[j], accre[r][j]);
                    accim[r][j] = fmaf(xs[r], bis[j], accim[r][j]);
                }
        }
    }

    __syncthreads();
    // ---- dump BX tile to LDS (canonical h index) ----
    #pragma unroll
    for (int r = 0; r < 8; ++r) {
        int t = ty * 8 + r;
        #pragma unroll
        for (int j = 0; j < 4; ++j) {
            int hl = (j < 2) ? (2 * tx + j) : (64 + 2 * tx + (j - 2));
            sb[t * 130 + hl] = make_float2(accre[r][j], accim[r][j]);
        }
    }
    __syncthreads();

    // ---- sequential complex scan over 64 steps, threads 0..127 = h ----
    if (tid < 128) {
        int hl = tid, hg = h0 + hl;
        float nu = expf(nu_log[hg]), th = expf(theta_log[hg]);
        float mag = expf(-nu);
        float lre = mag * cosf(th), lim = mag * sinf(th);
        float sre = 0.f, sim = 0.f;
        unsigned int* hout = hloc + (size_t)(b * TFULL + t0) * HIDDIM + h0 + hl;
        for (int t = 0; t < LCH; ++t) {
            float2 v = sb[t * 130 + hl];
            float nre = fmaf(lre, sre, fmaf(-lim, sim, v.x));
            float nim = fmaf(lre, sim, fmaf(lim, sre, v.y));
            sre = nre; sim = nim;
            hout[(size_t)t * HIDDIM] = pack2(sre, sim);
        }
        EC[((size_t)b * NCH + c) * HIDDIM + h0 + hl] = make_float2(sre, sim);
    }
}

// ---------------------------------------------------------------------------
// K2 (PROVEN round-1 serial carry, adapted in-place): EC: E -> exclusive
// carries, serial over 64 chunks per (b, h).
// ---------------------------------------------------------------------------
__global__ __launch_bounds__(256) void k_carry(
    const float* __restrict__ nu_log, const float* __restrict__ theta_log,
    float2* __restrict__ EC)
{
    int b = blockIdx.x, h = threadIdx.x;
    float nu = expf(nu_log[h]), th = expf(theta_log[h]);
    float m = expf(-(float)LCH * nu);
    float Lre = m * cosf((float)LCH * th);
    float Lim = m * sinf((float)LCH * th);
    float cre = 0.f, cim = 0.f;
    for (int c = 0; c < NCH; ++c) {
        size_t idx = ((size_t)b * NCH + c) * HIDDIM + h;
        float2 e = EC[idx];
        EC[idx] = make_float2(cre, cim);
        float nre = e.x + Lre * cre - Lim * cim;
        float nim = e.y + Lre * cim + Lim * cre;
        cre = nre; cim = nim;
    }
}

// ---------------------------------------------------------------------------
// K3 (UNDER TEST, round-4 verbatim): split-precision MFMA GEMM Y
// (M=64 t, N=128 o, K=640=[hre/him interleaved 512 | X 128]); carry fixup
// folded into A staging in fp32 before the hi/lo split.
// ---------------------------------------------------------------------------
__global__ __launch_bounds__(256) void k_y(
    const float* __restrict__ X, const unsigned int* __restrict__ hloc,
    const float2* __restrict__ EC, const float2* __restrict__ lampow,
    const unsigned short* __restrict__ Wy_hi,
    const unsigned short* __restrict__ Wy_lo, float* __restrict__ Y)
{
    __shared__ unsigned short sm[27648];  // 55296 B
    unsigned short* Ah = sm;              // [64][72]
    unsigned short* Al = sm + 4608;       // [64][72]
    unsigned short* Bh = sm + 9216;       // [128][72]
    unsigned short* Bl = sm + 18432;      // [128][72]
    __shared__ float2 carryS[256];

    const int tid = threadIdx.x;
    const int b = blockIdx.x >> 6, c = blockIdx.x & 63;
    const size_t rowbase = (size_t)(b * TFULL + c * LCH);

    carryS[tid] = EC[((size_t)b * NCH + c) * HIDDIM + tid];

    f32x4 acc[2][4];
    #pragma unroll
    for (int mi = 0; mi < 2; ++mi)
        #pragma unroll
        for (int nj = 0; nj < 4; ++nj) acc[mi][nj] = (f32x4){0.f, 0.f, 0.f, 0.f};

    const int w = tid >> 6, l = tid & 63;
    const int wm = w >> 1, wn = w & 1;
    const int lr = l & 15, lk = l >> 4;

    for (int kc = 0; kc < 10; ++kc) {
        __syncthreads();
        // ---- stage B hi/lo [128][72] from contiguous 16KB weight chunks ----
        {
            const uint4* sh = (const uint4*)(Wy_hi + kc * 8192);
            const uint4* sl = (const uint4*)(Wy_lo + kc * 8192);
            #pragma unroll
            for (int j = 0; j < 4; ++j) {
                uint4 vh = sh[tid + j * 256];
                uint4 vl = sl[tid + j * 256];
                int o = (tid >> 3) + 32 * j, kq = 8 * (tid & 7);
                *(uint4*)(Bh + o * 72 + kq) = vh;
                *(uint4*)(Bl + o * 72 + kq) = vl;
            }
        }
        // ---- stage A hi/lo [64][72] ----
        if (kc < 8) {
            #pragma unroll
            for (int s = 0; s < 2; ++s) {
                int f = s * 256 + tid;
                int t = f >> 3, slot = f & 7;
                uint4 u = *(const uint4*)(hloc + (rowbase + t) * HIDDIM + 32 * kc + 4 * slot);
                unsigned int* Arh = (unsigned int*)Ah + t * 36 + 4 * slot;
                unsigned int* Arl = (unsigned int*)Al + t * 36 + 4 * slot;
                const unsigned int* uu = (const unsigned int*)&u;
                #pragma unroll
                for (int e = 0; e < 4; ++e) {
                    int h = 32 * kc + 4 * slot + e;
                    float2 lp = lampow[t * HIDDIM + h];
                    float2 cr = carryS[h];
                    float hre = bflo(uu[e]) + lp.x * cr.x - lp.y * cr.y;
                    float him = bfhi(uu[e]) + lp.x * cr.y + lp.y * cr.x;
                    unsigned short rh, rl, ih, il;
                    split2(hre, rh, rl); split2(him, ih, il);
                    Arh[e] = ((unsigned int)ih << 16) | rh;
                    Arl[e] = ((unsigned int)il << 16) | rl;
                }
            }
        } else {
            int i0 = (kc - 8) * 64;
            #pragma unroll
            for (int s = 0; s < 4; ++s) {
                int f = s * 256 + tid;
                int t = f >> 4, slot = f & 15;
                float4 v = *(const float4*)(X + (rowbase + t) * INDIM + i0 + 4 * slot);
                unsigned short h0,l0,h1,l1,h2,l2,h3,l3;
                split2(v.x,h0,l0); split2(v.y,h1,l1); split2(v.z,h2,l2); split2(v.w,h3,l3);
                unsigned int* Arh = (unsigned int*)Ah + t * 36 + 2 * slot;
                unsigned int* Arl = (unsigned int*)Al + t * 36 + 2 * slot;
                Arh[0] = ((unsigned int)h1 << 16) | h0;
                Arh[1] = ((unsigned int)h3 << 16) | h2;
                Arl[0] = ((unsigned int)l1 << 16) | l0;
                Arl[1] = ((unsigned int)l3 << 16) | l2;
            }
        }
        __syncthreads();
        // ---- MFMA: 2 k-steps of 32, split-precision (3 products) ----
        #pragma unroll
        for (int ks = 0; ks < 2; ++ks) {
            short8 a0h = *(const short8*)(Ah + (32 * wm + lr) * 72 + 32 * ks + 8 * lk);
            short8 a1h = *(const short8*)(Ah + (32 * wm + 16 + lr) * 72 + 32 * ks + 8 * lk);
            short8 a0l = *(const short8*)(Al + (32 * wm + lr) * 72 + 32 * ks + 8 * lk);
            short8 a1l = *(const short8*)(Al + (32 * wm + 16 + lr) * 72 + 32 * ks + 8 * lk);
            #pragma unroll
            for (int nj = 0; nj < 4; ++nj) {
                short8 bh = *(const short8*)(Bh + (64 * wn + 16 * nj + lr) * 72 + 32 * ks + 8 * lk);
                short8 bl = *(const short8*)(Bl + (64 * wn + 16 * nj + lr) * 72 + 32 * ks + 8 * lk);
                acc[0][nj] = __builtin_amdgcn_mfma_f32_16x16x32_bf16(a0h, bh, acc[0][nj], 0, 0, 0);
                acc[0][nj] = __builtin_amdgcn_mfma_f32_16x16x32_bf16(a0h, bl, acc[0][nj], 0, 0, 0);
                acc[0][nj] = __builtin_amdgcn_mfma_f32_16x16x32_bf16(a0l, bh, acc[0][nj], 0, 0, 0);
                acc[1][nj] = __builtin_amdgcn_mfma_f32_16x16x32_bf16(a1h, bh, acc[1][nj], 0, 0, 0);
                acc[1][nj] = __builtin_amdgcn_mfma_f32_16x16x32_bf16(a1h, bl, acc[1][nj], 0, 0, 0);
                acc[1][nj] = __builtin_amdgcn_mfma_f32_16x16x32_bf16(a1l, bh, acc[1][nj], 0, 0, 0);
            }
        }
    }

    // ---- store Y ----
    float* Yb = Y + rowbase * OUTDIM;
    #pragma unroll
    for (int mi = 0; mi < 2; ++mi)
        #pragma unroll
        for (int nj = 0; nj < 4; ++nj)
            #pragma unroll
            for (int r = 0; r < 4; ++r) {
                int t = 32 * wm + 16 * mi + 4 * lk + r;
                int o = 64 * wn + 16 * nj + lr;
                Yb[(size_t)t * OUTDIM + o] = acc[mi][nj][r];
            }
}

// ---------------------------------------------------------------------------
extern "C" void kernel_launch(void* const* d_in, const int* in_sizes, int n_in,
                              void* d_out, int out_size, void* d_ws, size_t ws_size,
                              hipStream_t stream) {
    const float* X         = (const float*)d_in[0];
    const float* nu_log    = (const float*)d_in[1];
    const float* theta_log = (const float*)d_in[2];
    const float* B_re      = (const float*)d_in[3];
    const float* B_im      = (const float*)d_in[4];
    const float* C_re      = (const float*)d_in[5];
    const float* C_im      = (const float*)d_in[6];
    const float* D         = (const float*)d_in[7];
    float* Y = (float*)d_out;

    // workspace layout (35.49 MB)
    unsigned int*   hloc   = (unsigned int*)d_ws;                                 // 32 MB
    float2*         EC     = (float2*)((char*)d_ws + (size_t)33554432);           // 1 MB
    float2*         lampow = (float2*)((char*)d_ws + (size_t)34603008);           // 128 KB
    unsigned short* Wy_hi  = (unsigned short*)((char*)d_ws + (size_t)34996224);   // 160 KB
    unsigned short* Wy_lo  = (unsigned short*)((char*)d_ws + (size_t)35160064);   // 160 KB

    hipLaunchKernelGGL(k_prep, dim3(384), dim3(256), 0, stream,
                       nu_log, theta_log, C_re, C_im, D, Wy_hi, Wy_lo, lampow);
    hipLaunchKernelGGL(k_bx_scan, dim3(NBATCH * NCH * 2), dim3(256), 0, stream,
                       X, nu_log, theta_log, B_re, B_im, hloc, EC);
    hipLaunchKernelGGL(k_carry, dim3(NBATCH), dim3(256), 0, stream,
                       nu_log, theta_log, EC);
    hipLaunchKernelGGL(k_y, dim3(NBATCH * NCH), dim3(256), 0, stream,
                       X, hloc, EC, lampow, Wy_hi, Wy_lo, Y);
}

// Round 6
// 154.085 us; speedup vs baseline: 1.5173x; 1.1342x over previous
//
#include <hip/hip_runtime.h>
#include <hip/hip_bf16.h>

#define TFULL 4096
#define NBATCH 8
#define INDIM 128
#define OUTDIM 128
#define HIDDIM 256
#define LCH 64
#define NCH (TFULL / LCH)   // 64

typedef float f32x4 __attribute__((ext_vector_type(4)));
typedef short short8 __attribute__((ext_vector_type(8)));

static __device__ __forceinline__ unsigned short f2bf(float f) {
    unsigned int x = __float_as_uint(f);
    x += 0x7fffu + ((x >> 16) & 1u);   // round-to-nearest-even
    return (unsigned short)(x >> 16);
}
// split fp32 into hi/lo bf16 pair (v ~= hi + lo to ~16.5 mantissa bits)
static __device__ __forceinline__ void split2(float v, unsigned short& hi, unsigned short& lo) {
    hi = f2bf(v);
    lo = f2bf(v - __uint_as_float((unsigned int)hi << 16));
}

// ---------------------------------------------------------------------------
// K0 (R2 verbatim): precompute hi/lo bf16 weights + lam^(t+1) table.
//  Wbx [half][kc=4][n=256][kk=32] : g=n>>6: h=128*half+64*(g>>1)+(n&63);
//      g&1 ? gamma*B_im : gamma*B_re
//  Wy  [kc=10][o=128][kk=64] : k=64*kc+kk; k<512: (k&1? -C_im : C_re)[o][k>>1]
//      else D[o][k-512]
//  lampow [64][256] float2 = lam^(tl+1)
// ---------------------------------------------------------------------------
__global__ __launch_bounds__(256) void k_prep(
    const float* __restrict__ nu_log, const float* __restrict__ theta_log,
    const float* __restrict__ B_re, const float* __restrict__ B_im,
    const float* __restrict__ C_re, const float* __restrict__ C_im,
    const float* __restrict__ D,
    unsigned short* __restrict__ Wbx_hi, unsigned short* __restrict__ Wbx_lo,
    unsigned short* __restrict__ Wy_hi, unsigned short* __restrict__ Wy_lo,
    float2* __restrict__ lampow)
{
    int f = blockIdx.x * 256 + threadIdx.x;   // grid 640 -> f < 163840
    if (f < 65536) {
        int kk = f & 31, n = (f >> 5) & 255, kc = (f >> 13) & 3, half = f >> 15;
        int g = n >> 6;
        int h = 128 * half + 64 * (g >> 1) + (n & 63);
        int i = 32 * kc + kk;
        float mag = expf(-expf(nu_log[h]));
        float gam = sqrtf(fmaxf(0.f, 1.f - mag * mag));
        float v = gam * ((g & 1) ? B_im[h * INDIM + i] : B_re[h * INDIM + i]);
        unsigned short hi, lo; split2(v, hi, lo);
        Wbx_hi[f] = hi; Wbx_lo[f] = lo;
    } else if (f < 147456) {
        int q = f - 65536;
        int kk = q & 63, o = (q >> 6) & 127, kc = q >> 13;
        int k = 64 * kc + kk;
        float v;
        if (k < 512) {
            int h = k >> 1;
            v = (k & 1) ? -C_im[o * HIDDIM + h] : C_re[o * HIDDIM + h];
        } else {
            v = D[o * INDIM + (k - 512)];
        }
        unsigned short hi, lo; split2(v, hi, lo);
        Wy_hi[q] = hi; Wy_lo[q] = lo;
    } else {
        int l = f - 147456;                   // [0, 16384)
        int h = l & 255, tl = l >> 8;
        float nu = expf(nu_log[h]), th = expf(theta_log[h]);
        float kf = (float)(tl + 1);
        float m = expf(-kf * nu);
        lampow[l] = make_float2(m * cosf(kf * th), m * sinf(kf * th));
    }
}

// ---------------------------------------------------------------------------
// K1a: split-precision MFMA GEMM BX (M=64 t, N=256=[re64|im64|re64|im64],
//      K=128) for one (b, chunk, h-half). Structural clone of the PROVEN k_y
//      loop: per K-chunk {barrier; stage A+B hi/lo; barrier; read frags; MFMA}.
//      No LDS aliasing, no time-sharing. Writes BX fp32 float2 to ws.
// ---------------------------------------------------------------------------
__global__ __launch_bounds__(256) void k_bx(
    const float* __restrict__ X,
    const unsigned short* __restrict__ Wbx_hi,
    const unsigned short* __restrict__ Wbx_lo,
    float2* __restrict__ BX)
{
    __shared__ unsigned short sm[25600];   // 51200 B
    unsigned short* Ash = sm;              // [64][40]
    unsigned short* Asl = sm + 2560;       // [64][40]
    unsigned short* Bsh = sm + 5120;       // [256][40]
    unsigned short* Bsl = sm + 15360;      // [256][40]

    const int tid = threadIdx.x;
    const int blk = blockIdx.x;
    const int b = blk >> 7, c = (blk >> 1) & 63, half = blk & 1;
    const size_t rowbase = (size_t)(b * TFULL + c * LCH);

    f32x4 acc[2][8];
    #pragma unroll
    for (int mi = 0; mi < 2; ++mi)
        #pragma unroll
        for (int j = 0; j < 8; ++j) acc[mi][j] = (f32x4){0.f, 0.f, 0.f, 0.f};

    const int w = tid >> 6, l = tid & 63;
    const int wm = w >> 1, wn = w & 1;
    const int lr = l & 15, lk = l >> 4;
    const unsigned short* wch_h = Wbx_hi + half * 32768;
    const unsigned short* wch_l = Wbx_lo + half * 32768;

    for (int kc = 0; kc < 4; ++kc) {
        __syncthreads();
        // ---- stage B hi/lo [256][40] from contiguous 16KB weight chunks ----
        {
            const uint4* sh = (const uint4*)(wch_h + kc * 8192);
            const uint4* sl = (const uint4*)(wch_l + kc * 8192);
            #pragma unroll
            for (int j = 0; j < 4; ++j) {
                uint4 vh = sh[tid + j * 256];
                uint4 vl = sl[tid + j * 256];
                int n = (tid >> 2) + 64 * j, kq = 8 * (tid & 3);
                *(uint4*)(Bsh + n * 40 + kq) = vh;
                *(uint4*)(Bsl + n * 40 + kq) = vl;
            }
        }
        // ---- stage A hi/lo [64][40] = split-bf16(X chunk cols 32kc..+32) ----
        {
            int t = tid >> 2, q = tid & 3;
            const float* Xr = X + (rowbase + t) * INDIM + 32 * kc + 8 * q;
            float4 v0 = *(const float4*)(Xr);
            float4 v1 = *(const float4*)(Xr + 4);
            float xs[8] = {v0.x, v0.y, v0.z, v0.w, v1.x, v1.y, v1.z, v1.w};
            unsigned int* Ah32 = (unsigned int*)Ash + t * 20 + 4 * q;
            unsigned int* Al32 = (unsigned int*)Asl + t * 20 + 4 * q;
            #pragma unroll
            for (int e = 0; e < 4; ++e) {
                unsigned short h0, l0, h1, l1;
                split2(xs[2 * e], h0, l0);
                split2(xs[2 * e + 1], h1, l1);
                Ah32[e] = ((unsigned int)h1 << 16) | h0;
                Al32[e] = ((unsigned int)l1 << 16) | l0;
            }
        }
        __syncthreads();
        // ---- MFMA: split-precision (3 products) ----
        short8 a0h = *(const short8*)(Ash + (32 * wm + lr) * 40 + 8 * lk);
        short8 a1h = *(const short8*)(Ash + (32 * wm + 16 + lr) * 40 + 8 * lk);
        short8 a0l = *(const short8*)(Asl + (32 * wm + lr) * 40 + 8 * lk);
        short8 a1l = *(const short8*)(Asl + (32 * wm + 16 + lr) * 40 + 8 * lk);
        #pragma unroll
        for (int j = 0; j < 8; ++j) {
            short8 bh = *(const short8*)(Bsh + (128 * wn + 16 * j + lr) * 40 + 8 * lk);
            short8 bl = *(const short8*)(Bsl + (128 * wn + 16 * j + lr) * 40 + 8 * lk);
            acc[0][j] = __builtin_amdgcn_mfma_f32_16x16x32_bf16(a0h, bh, acc[0][j], 0, 0, 0);
            acc[0][j] = __builtin_amdgcn_mfma_f32_16x16x32_bf16(a0l, bh, acc[0][j], 0, 0, 0);
            acc[0][j] = __builtin_amdgcn_mfma_f32_16x16x32_bf16(a0h, bl, acc[0][j], 0, 0, 0);
            acc[1][j] = __builtin_amdgcn_mfma_f32_16x16x32_bf16(a1h, bh, acc[1][j], 0, 0, 0);
            acc[1][j] = __builtin_amdgcn_mfma_f32_16x16x32_bf16(a1l, bh, acc[1][j], 0, 0, 0);
            acc[1][j] = __builtin_amdgcn_mfma_f32_16x16x32_bf16(a1h, bl, acc[1][j], 0, 0, 0);
        }
    }

    // ---- store BX fp32: h = 128*half + 64*wn + 16*j + lr ----
    #pragma unroll
    for (int mi = 0; mi < 2; ++mi)
        #pragma unroll
        for (int j = 0; j < 4; ++j)
            #pragma unroll
            for (int r = 0; r < 4; ++r) {
                int t = 32 * wm + 16 * mi + 4 * lk + r;
                int h = 128 * half + 64 * wn + 16 * j + lr;
                BX[(rowbase + t) * HIDDIM + h] =
                    make_float2(acc[mi][j][r], acc[mi][j + 4][r]);
            }
}

// ---------------------------------------------------------------------------
// K1b: LDS-free sequential scan. Block=(b,chunk), thread=h. Reads BX fp32
//      (coalesced 2KB/step), 64-step fp32 recurrence, overwrites BX in place
//      with the fp32 hidden state (same thread, same address). Chunk-end -> EC.
// ---------------------------------------------------------------------------
__global__ __launch_bounds__(256) void k_scan(
    const float* __restrict__ nu_log, const float* __restrict__ theta_log,
    float2* __restrict__ BX, float2* __restrict__ EC)
{
    const int b = blockIdx.x >> 6, c = blockIdx.x & 63;
    const int h = threadIdx.x;
    const size_t rowbase = (size_t)(b * TFULL + c * LCH);

    float nu = expf(nu_log[h]), th = expf(theta_log[h]);
    float mag = expf(-nu);
    float lre = mag * cosf(th), lim = mag * sinf(th);
    float sre = 0.f, sim = 0.f;
    float2* p = BX + rowbase * HIDDIM + h;
    for (int t = 0; t < LCH; ++t) {
        float2 v = p[(size_t)t * HIDDIM];
        float nre = fmaf(lre, sre, fmaf(-lim, sim, v.x));
        float nim = fmaf(lre, sim, fmaf(lim, sre, v.y));
        sre = nre; sim = nim;
        p[(size_t)t * HIDDIM] = make_float2(sre, sim);
    }
    EC[((size_t)b * NCH + c) * HIDDIM + h] = make_float2(sre, sim);
}

// ---------------------------------------------------------------------------
// K2 (PROVEN serial carry): EC: E -> exclusive carries, serial over 64 chunks.
// ---------------------------------------------------------------------------
__global__ __launch_bounds__(256) void k_carry(
    const float* __restrict__ nu_log, const float* __restrict__ theta_log,
    float2* __restrict__ EC)
{
    int b = blockIdx.x, h = threadIdx.x;
    float nu = expf(nu_log[h]), th = expf(theta_log[h]);
    float m = expf(-(float)LCH * nu);
    float Lre = m * cosf((float)LCH * th);
    float Lim = m * sinf((float)LCH * th);
    float cre = 0.f, cim = 0.f;
    for (int c = 0; c < NCH; ++c) {
        size_t idx = ((size_t)b * NCH + c) * HIDDIM + h;
        float2 e = EC[idx];
        EC[idx] = make_float2(cre, cim);
        float nre = e.x + Lre * cre - Lim * cim;
        float nim = e.y + Lre * cim + Lim * cre;
        cre = nre; cim = nim;
    }
}

// ---------------------------------------------------------------------------
// K3 (PROVEN, A-staging reads fp32 h from BX now): split-precision MFMA GEMM Y
// (M=64 t, N=128 o, K=640=[hre/him interleaved 512 | X 128]); carry fixup
// folded into A staging in fp32 before the hi/lo split.
// ---------------------------------------------------------------------------
__global__ __launch_bounds__(256) void k_y(
    const float* __restrict__ X, const float2* __restrict__ BXh,
    const float2* __restrict__ EC, const float2* __restrict__ lampow,
    const unsigned short* __restrict__ Wy_hi,
    const unsigned short* __restrict__ Wy_lo, float* __restrict__ Y)
{
    __shared__ unsigned short sm[27648];  // 55296 B
    unsigned short* Ah = sm;              // [64][72]
    unsigned short* Al = sm + 4608;       // [64][72]
    unsigned short* Bh = sm + 9216;       // [128][72]
    unsigned short* Bl = sm + 18432;      // [128][72]
    __shared__ float2 carryS[256];

    const int tid = threadIdx.x;
    const int b = blockIdx.x >> 6, c = blockIdx.x & 63;
    const size_t rowbase = (size_t)(b * TFULL + c * LCH);

    carryS[tid] = EC[((size_t)b * NCH + c) * HIDDIM + tid];

    f32x4 acc[2][4];
    #pragma unroll
    for (int mi = 0; mi < 2; ++mi)
        #pragma unroll
        for (int nj = 0; nj < 4; ++nj) acc[mi][nj] = (f32x4){0.f, 0.f, 0.f, 0.f};

    const int w = tid >> 6, l = tid & 63;
    const int wm = w >> 1, wn = w & 1;
    const int lr = l & 15, lk = l >> 4;

    for (int kc = 0; kc < 10; ++kc) {
        __syncthreads();
        // ---- stage B hi/lo [128][72] from contiguous 16KB weight chunks ----
        {
            const uint4* sh = (const uint4*)(Wy_hi + kc * 8192);
            const uint4* sl = (const uint4*)(Wy_lo + kc * 8192);
            #pragma unroll
            for (int j = 0; j < 4; ++j) {
                uint4 vh = sh[tid + j * 256];
                uint4 vl = sl[tid + j * 256];
                int o = (tid >> 3) + 32 * j, kq = 8 * (tid & 7);
                *(uint4*)(Bh + o * 72 + kq) = vh;
                *(uint4*)(Bl + o * 72 + kq) = vl;
            }
        }
        // ---- stage A hi/lo [64][72] ----
        if (kc < 8) {
            #pragma unroll
            for (int s = 0; s < 2; ++s) {
                int f = s * 256 + tid;
                int t = f >> 3, slot = f & 7;
                const float4* hp =
                    (const float4*)(BXh + (rowbase + t) * HIDDIM + 32 * kc + 4 * slot);
                float4 p0 = hp[0], p1 = hp[1];
                float hv[8] = {p0.x, p0.y, p0.z, p0.w, p1.x, p1.y, p1.z, p1.w};
                unsigned int* Arh = (unsigned int*)Ah + t * 36 + 4 * slot;
                unsigned int* Arl = (unsigned int*)Al + t * 36 + 4 * slot;
                #pragma unroll
                for (int e = 0; e < 4; ++e) {
                    int h = 32 * kc + 4 * slot + e;
                    float2 lp = lampow[t * HIDDIM + h];
                    float2 cr = carryS[h];
                    float hre = hv[2 * e]     + lp.x * cr.x - lp.y * cr.y;
                    float him = hv[2 * e + 1] + lp.x * cr.y + lp.y * cr.x;
                    unsigned short rh, rl, ih, il;
                    split2(hre, rh, rl); split2(him, ih, il);
                    Arh[e] = ((unsigned int)ih << 16) | rh;
                    Arl[e] = ((unsigned int)il << 16) | rl;
                }
            }
        } else {
            int i0 = (kc - 8) * 64;
            #pragma unroll
            for (int s = 0; s < 4; ++s) {
                int f = s * 256 + tid;
                int t = f >> 4, slot = f & 15;
                float4 v = *(const float4*)(X + (rowbase + t) * INDIM + i0 + 4 * slot);
                unsigned short h0,l0,h1,l1,h2,l2,h3,l3;
                split2(v.x,h0,l0); split2(v.y,h1,l1); split2(v.z,h2,l2); split2(v.w,h3,l3);
                unsigned int* Arh = (unsigned int*)Ah + t * 36 + 2 * slot;
                unsigned int* Arl = (unsigned int*)Al + t * 36 + 2 * slot;
                Arh[0] = ((unsigned int)h1 << 16) | h0;
                Arh[1] = ((unsigned int)h3 << 16) | h2;
                Arl[0] = ((unsigned int)l1 << 16) | l0;
                Arl[1] = ((unsigned int)l3 << 16) | l2;
            }
        }
        __syncthreads();
        // ---- MFMA: 2 k-steps of 32, split-precision (3 products) ----
        #pragma unroll
        for (int ks = 0; ks < 2; ++ks) {
            short8 a0h = *(const short8*)(Ah + (32 * wm + lr) * 72 + 32 * ks + 8 * lk);
            short8 a1h = *(const short8*)(Ah + (32 * wm + 16 + lr) * 72 + 32 * ks + 8 * lk);
            short8 a0l = *(const short8*)(Al + (32 * wm + lr) * 72 + 32 * ks + 8 * lk);
            short8 a1l = *(const short8*)(Al + (32 * wm + 16 + lr) * 72 + 32 * ks + 8 * lk);
            #pragma unroll
            for (int nj = 0; nj < 4; ++nj) {
                short8 bh = *(const short8*)(Bh + (64 * wn + 16 * nj + lr) * 72 + 32 * ks + 8 * lk);
                short8 bl = *(const short8*)(Bl + (64 * wn + 16 * nj + lr) * 72 + 32 * ks + 8 * lk);
                acc[0][nj] = __builtin_amdgcn_mfma_f32_16x16x32_bf16(a0h, bh, acc[0][nj], 0, 0, 0);
                acc[0][nj] = __builtin_amdgcn_mfma_f32_16x16x32_bf16(a0h, bl, acc[0][nj], 0, 0, 0);
                acc[0][nj] = __builtin_amdgcn_mfma_f32_16x16x32_bf16(a0l, bh, acc[0][nj], 0, 0, 0);
                acc[1][nj] = __builtin_amdgcn_mfma_f32_16x16x32_bf16(a1h, bh, acc[1][nj], 0, 0, 0);
                acc[1][nj] = __builtin_amdgcn_mfma_f32_16x16x32_bf16(a1h, bl, acc[1][nj], 0, 0, 0);
                acc[1][nj] = __builtin_amdgcn_mfma_f32_16x16x32_bf16(a1l, bh, acc[1][nj], 0, 0, 0);
            }
        }
    }

    // ---- store Y ----
    float* Yb = Y + rowbase * OUTDIM;
    #pragma unroll
    for (int mi = 0; mi < 2; ++mi)
        #pragma unroll
        for (int nj = 0; nj < 4; ++nj)
            #pragma unroll
            for (int r = 0; r < 4; ++r) {
                int t = 32 * wm + 16 * mi + 4 * lk + r;
                int o = 64 * wn + 16 * nj + lr;
                Yb[(size_t)t * OUTDIM + o] = acc[mi][nj][r];
            }
}

// ---------------------------------------------------------------------------
extern "C" void kernel_launch(void* const* d_in, const int* in_sizes, int n_in,
                              void* d_out, int out_size, void* d_ws, size_t ws_size,
                              hipStream_t stream) {
    const float* X         = (const float*)d_in[0];
    const float* nu_log    = (const float*)d_in[1];
    const float* theta_log = (const float*)d_in[2];
    const float* B_re      = (const float*)d_in[3];
    const float* B_im      = (const float*)d_in[4];
    const float* C_re      = (const float*)d_in[5];
    const float* C_im      = (const float*)d_in[6];
    const float* D         = (const float*)d_in[7];
    float* Y = (float*)d_out;

    // workspace layout (65.7 MB)
    float2*         BX     = (float2*)d_ws;                                       // 64 MB (BX -> h in place)
    float2*         EC     = (float2*)((char*)d_ws + (size_t)67108864);           // 1 MB
    float2*         lampow = (float2*)((char*)d_ws + (size_t)68157440);           // 128 KB
    unsigned short* Wbx_hi = (unsigned short*)((char*)d_ws + (size_t)68288512);   // 128 KB
    unsigned short* Wbx_lo = (unsigned short*)((char*)d_ws + (size_t)68419584);   // 128 KB
    unsigned short* Wy_hi  = (unsigned short*)((char*)d_ws + (size_t)68550656);   // 160 KB
    unsigned short* Wy_lo  = (unsigned short*)((char*)d_ws + (size_t)68714496);   // 160 KB

    hipLaunchKernelGGL(k_prep, dim3(640), dim3(256), 0, stream,
                       nu_log, theta_log, B_re, B_im, C_re, C_im, D,
                       Wbx_hi, Wbx_lo, Wy_hi, Wy_lo, lampow);
    hipLaunchKernelGGL(k_bx, dim3(NBATCH * NCH * 2), dim3(256), 0, stream,
                       X, Wbx_hi, Wbx_lo, BX);
    hipLaunchKernelGGL(k_scan, dim3(NBATCH * NCH), dim3(256), 0, stream,
                       nu_log, theta_log, BX, EC);
    hipLaunchKernelGGL(k_carry, dim3(NBATCH), dim3(256), 0, stream,
                       nu_log, theta_log, EC);
    hipLaunchKernelGGL(k_y, dim3(NBATCH * NCH), dim3(256), 0, stream,
                       X, BX, EC, lampow, Wy_hi, Wy_lo, Y);
}

// Round 7
// 148.365 us; speedup vs baseline: 1.5758x; 1.0386x over previous
//
#include <hip/hip_runtime.h>
#include <hip/hip_bf16.h>

#define TFULL 4096
#define NBATCH 8
#define INDIM 128
#define OUTDIM 128
#define HIDDIM 256
#define LCH 64
#define NCH (TFULL / LCH)   // 64

typedef float f32x4 __attribute__((ext_vector_type(4)));
typedef short short8 __attribute__((ext_vector_type(8)));

static __device__ __forceinline__ unsigned short f2bf(float f) {
    unsigned int x = __float_as_uint(f);
    x += 0x7fffu + ((x >> 16) & 1u);   // round-to-nearest-even
    return (unsigned short)(x >> 16);
}
static __device__ __forceinline__ unsigned int pack2(float a, float b) {
    return ((unsigned int)f2bf(b) << 16) | (unsigned int)f2bf(a);
}
static __device__ __forceinline__ float bflo(unsigned int u) {
    return __uint_as_float(u << 16);
}
static __device__ __forceinline__ float bfhi(unsigned int u) {
    return __uint_as_float(u & 0xffff0000u);
}
// split fp32 into hi/lo bf16 pair (v ~= hi + lo to ~16.5 mantissa bits)
static __device__ __forceinline__ void split2(float v, unsigned short& hi, unsigned short& lo) {
    hi = f2bf(v);
    lo = f2bf(v - __uint_as_float((unsigned int)hi << 16));
}

// ---------------------------------------------------------------------------
// K0 (proven): precompute hi/lo bf16 weights + lam^(t+1) table.
// ---------------------------------------------------------------------------
__global__ __launch_bounds__(256) void k_prep(
    const float* __restrict__ nu_log, const float* __restrict__ theta_log,
    const float* __restrict__ B_re, const float* __restrict__ B_im,
    const float* __restrict__ C_re, const float* __restrict__ C_im,
    const float* __restrict__ D,
    unsigned short* __restrict__ Wbx_hi, unsigned short* __restrict__ Wbx_lo,
    unsigned short* __restrict__ Wy_hi, unsigned short* __restrict__ Wy_lo,
    float2* __restrict__ lampow)
{
    int f = blockIdx.x * 256 + threadIdx.x;   // grid 640 -> f < 163840
    if (f < 65536) {
        int kk = f & 31, n = (f >> 5) & 255, kc = (f >> 13) & 3, half = f >> 15;
        int g = n >> 6;
        int h = 128 * half + 64 * (g >> 1) + (n & 63);
        int i = 32 * kc + kk;
        float mag = expf(-expf(nu_log[h]));
        float gam = sqrtf(fmaxf(0.f, 1.f - mag * mag));
        float v = gam * ((g & 1) ? B_im[h * INDIM + i] : B_re[h * INDIM + i]);
        unsigned short hi, lo; split2(v, hi, lo);
        Wbx_hi[f] = hi; Wbx_lo[f] = lo;
    } else if (f < 147456) {
        int q = f - 65536;
        int kk = q & 63, o = (q >> 6) & 127, kc = q >> 13;
        int k = 64 * kc + kk;
        float v;
        if (k < 512) {
            int h = k >> 1;
            v = (k & 1) ? -C_im[o * HIDDIM + h] : C_re[o * HIDDIM + h];
        } else {
            v = D[o * INDIM + (k - 512)];
        }
        unsigned short hi, lo; split2(v, hi, lo);
        Wy_hi[q] = hi; Wy_lo[q] = lo;
    } else {
        int l = f - 147456;                   // [0, 16384)
        int h = l & 255, tl = l >> 8;
        float nu = expf(nu_log[h]), th = expf(theta_log[h]);
        float kf = (float)(tl + 1);
        float m = expf(-kf * nu);
        lampow[l] = make_float2(m * cosf(kf * th), m * sinf(kf * th));
    }
}

// ---------------------------------------------------------------------------
// K1a (proven R6): split-precision MFMA GEMM BX (M=64 t, N=256, K=128) for
//      one (b, chunk, h-half). Writes BX fp32 float2 to ws.
// ---------------------------------------------------------------------------
__global__ __launch_bounds__(256) void k_bx(
    const float* __restrict__ X,
    const unsigned short* __restrict__ Wbx_hi,
    const unsigned short* __restrict__ Wbx_lo,
    float2* __restrict__ BX)
{
    __shared__ unsigned short sm[25600];   // 51200 B
    unsigned short* Ash = sm;              // [64][40]
    unsigned short* Asl = sm + 2560;       // [64][40]
    unsigned short* Bsh = sm + 5120;       // [256][40]
    unsigned short* Bsl = sm + 15360;      // [256][40]

    const int tid = threadIdx.x;
    const int blk = blockIdx.x;
    const int b = blk >> 7, c = (blk >> 1) & 63, half = blk & 1;
    const size_t rowbase = (size_t)(b * TFULL + c * LCH);

    f32x4 acc[2][8];
    #pragma unroll
    for (int mi = 0; mi < 2; ++mi)
        #pragma unroll
        for (int j = 0; j < 8; ++j) acc[mi][j] = (f32x4){0.f, 0.f, 0.f, 0.f};

    const int w = tid >> 6, l = tid & 63;
    const int wm = w >> 1, wn = w & 1;
    const int lr = l & 15, lk = l >> 4;
    const unsigned short* wch_h = Wbx_hi + half * 32768;
    const unsigned short* wch_l = Wbx_lo + half * 32768;

    for (int kc = 0; kc < 4; ++kc) {
        __syncthreads();
        // ---- stage B hi/lo [256][40] from contiguous 16KB weight chunks ----
        {
            const uint4* sh = (const uint4*)(wch_h + kc * 8192);
            const uint4* sl = (const uint4*)(wch_l + kc * 8192);
            #pragma unroll
            for (int j = 0; j < 4; ++j) {
                uint4 vh = sh[tid + j * 256];
                uint4 vl = sl[tid + j * 256];
                int n = (tid >> 2) + 64 * j, kq = 8 * (tid & 3);
                *(uint4*)(Bsh + n * 40 + kq) = vh;
                *(uint4*)(Bsl + n * 40 + kq) = vl;
            }
        }
        // ---- stage A hi/lo [64][40] = split-bf16(X chunk cols 32kc..+32) ----
        {
            int t = tid >> 2, q = tid & 3;
            const float* Xr = X + (rowbase + t) * INDIM + 32 * kc + 8 * q;
            float4 v0 = *(const float4*)(Xr);
            float4 v1 = *(const float4*)(Xr + 4);
            float xs[8] = {v0.x, v0.y, v0.z, v0.w, v1.x, v1.y, v1.z, v1.w};
            unsigned int* Ah32 = (unsigned int*)Ash + t * 20 + 4 * q;
            unsigned int* Al32 = (unsigned int*)Asl + t * 20 + 4 * q;
            #pragma unroll
            for (int e = 0; e < 4; ++e) {
                unsigned short h0, l0, h1, l1;
                split2(xs[2 * e], h0, l0);
                split2(xs[2 * e + 1], h1, l1);
                Ah32[e] = ((unsigned int)h1 << 16) | h0;
                Al32[e] = ((unsigned int)l1 << 16) | l0;
            }
        }
        __syncthreads();
        // ---- MFMA: split-precision (3 products) ----
        short8 a0h = *(const short8*)(Ash + (32 * wm + lr) * 40 + 8 * lk);
        short8 a1h = *(const short8*)(Ash + (32 * wm + 16 + lr) * 40 + 8 * lk);
        short8 a0l = *(const short8*)(Asl + (32 * wm + lr) * 40 + 8 * lk);
        short8 a1l = *(const short8*)(Asl + (32 * wm + 16 + lr) * 40 + 8 * lk);
        #pragma unroll
        for (int j = 0; j < 8; ++j) {
            short8 bh = *(const short8*)(Bsh + (128 * wn + 16 * j + lr) * 40 + 8 * lk);
            short8 bl = *(const short8*)(Bsl + (128 * wn + 16 * j + lr) * 40 + 8 * lk);
            acc[0][j] = __builtin_amdgcn_mfma_f32_16x16x32_bf16(a0h, bh, acc[0][j], 0, 0, 0);
            acc[0][j] = __builtin_amdgcn_mfma_f32_16x16x32_bf16(a0l, bh, acc[0][j], 0, 0, 0);
            acc[0][j] = __builtin_amdgcn_mfma_f32_16x16x32_bf16(a0h, bl, acc[0][j], 0, 0, 0);
            acc[1][j] = __builtin_amdgcn_mfma_f32_16x16x32_bf16(a1h, bh, acc[1][j], 0, 0, 0);
            acc[1][j] = __builtin_amdgcn_mfma_f32_16x16x32_bf16(a1l, bh, acc[1][j], 0, 0, 0);
            acc[1][j] = __builtin_amdgcn_mfma_f32_16x16x32_bf16(a1h, bl, acc[1][j], 0, 0, 0);
        }
    }

    // ---- store BX fp32: h = 128*half + 64*wn + 16*j + lr ----
    #pragma unroll
    for (int mi = 0; mi < 2; ++mi)
        #pragma unroll
        for (int j = 0; j < 4; ++j)
            #pragma unroll
            for (int r = 0; r < 4; ++r) {
                int t = 32 * wm + 16 * mi + 4 * lk + r;
                int h = 128 * half + 64 * wn + 16 * j + lr;
                BX[(rowbase + t) * HIDDIM + h] =
                    make_float2(acc[mi][j][r], acc[mi][j + 4][r]);
            }
}

// ---------------------------------------------------------------------------
// K1b: pipelined sequential scan. Block=(b,chunk), thread=h. Loads batched
//      8-at-a-time (state-independent -> latency overlapped); fp32 recurrence;
//      h stored bf16x2 to hloc (R5-proven format). Chunk-end -> EC fp32.
// ---------------------------------------------------------------------------
__global__ __launch_bounds__(256) void k_scan(
    const float* __restrict__ nu_log, const float* __restrict__ theta_log,
    const float2* __restrict__ BX, unsigned int* __restrict__ hloc,
    float2* __restrict__ EC)
{
    const int b = blockIdx.x >> 6, c = blockIdx.x & 63;
    const int h = threadIdx.x;
    const size_t rowbase = (size_t)(b * TFULL + c * LCH);

    float nu = expf(nu_log[h]), th = expf(theta_log[h]);
    float mag = expf(-nu);
    float lre = mag * cosf(th), lim = mag * sinf(th);
    float sre = 0.f, sim = 0.f;
    const float2* p = BX + rowbase * HIDDIM + h;
    unsigned int* q = hloc + rowbase * HIDDIM + h;
    for (int t0 = 0; t0 < LCH; t0 += 8) {
        float2 v[8];
        #pragma unroll
        for (int j = 0; j < 8; ++j) v[j] = p[(size_t)(t0 + j) * HIDDIM];
        unsigned int o[8];
        #pragma unroll
        for (int j = 0; j < 8; ++j) {
            float nre = fmaf(lre, sre, fmaf(-lim, sim, v[j].x));
            float nim = fmaf(lre, sim, fmaf(lim, sre, v[j].y));
            sre = nre; sim = nim;
            o[j] = pack2(sre, sim);
        }
        #pragma unroll
        for (int j = 0; j < 8; ++j) q[(size_t)(t0 + j) * HIDDIM] = o[j];
    }
    EC[((size_t)b * NCH + c) * HIDDIM + h] = make_float2(sre, sim);
}

// ---------------------------------------------------------------------------
// K2: serial carry (proven arithmetic), software-pipelined: batch-load 8 E's,
//     8-step recurrence in registers, batch-store exclusive carries.
// ---------------------------------------------------------------------------
__global__ __launch_bounds__(256) void k_carry(
    const float* __restrict__ nu_log, const float* __restrict__ theta_log,
    float2* __restrict__ EC)
{
    int b = blockIdx.x, h = threadIdx.x;
    float nu = expf(nu_log[h]), th = expf(theta_log[h]);
    float m = expf(-(float)LCH * nu);
    float Lre = m * cosf((float)LCH * th);
    float Lim = m * sinf((float)LCH * th);
    float cre = 0.f, cim = 0.f;
    float2* base = EC + (size_t)b * NCH * HIDDIM + h;
    for (int c0 = 0; c0 < NCH; c0 += 8) {
        float2 e[8];
        #pragma unroll
        for (int j = 0; j < 8; ++j) e[j] = base[(size_t)(c0 + j) * HIDDIM];
        float2 wv[8];
        #pragma unroll
        for (int j = 0; j < 8; ++j) {
            wv[j] = make_float2(cre, cim);
            float nre = e[j].x + Lre * cre - Lim * cim;
            float nim = e[j].y + Lre * cim + Lim * cre;
            cre = nre; cim = nim;
        }
        #pragma unroll
        for (int j = 0; j < 8; ++j) base[(size_t)(c0 + j) * HIDDIM] = wv[j];
    }
}

// ---------------------------------------------------------------------------
// K3 (R5-proven verbatim): split-precision MFMA GEMM Y (M=64 t, N=128 o,
//     K=640=[hre/him interleaved 512 | X 128]); reads bf16x2 hloc; carry
//     fixup folded into A staging in fp32 before the hi/lo split.
// ---------------------------------------------------------------------------
__global__ __launch_bounds__(256) void k_y(
    const float* __restrict__ X, const unsigned int* __restrict__ hloc,
    const float2* __restrict__ EC, const float2* __restrict__ lampow,
    const unsigned short* __restrict__ Wy_hi,
    const unsigned short* __restrict__ Wy_lo, float* __restrict__ Y)
{
    __shared__ unsigned short sm[27648];  // 55296 B
    unsigned short* Ah = sm;              // [64][72]
    unsigned short* Al = sm + 4608;       // [64][72]
    unsigned short* Bh = sm + 9216;       // [128][72]
    unsigned short* Bl = sm + 18432;      // [128][72]
    __shared__ float2 carryS[256];

    const int tid = threadIdx.x;
    const int b = blockIdx.x >> 6, c = blockIdx.x & 63;
    const size_t rowbase = (size_t)(b * TFULL + c * LCH);

    carryS[tid] = EC[((size_t)b * NCH + c) * HIDDIM + tid];

    f32x4 acc[2][4];
    #pragma unroll
    for (int mi = 0; mi < 2; ++mi)
        #pragma unroll
        for (int nj = 0; nj < 4; ++nj) acc[mi][nj] = (f32x4){0.f, 0.f, 0.f, 0.f};

    const int w = tid >> 6, l = tid & 63;
    const int wm = w >> 1, wn = w & 1;
    const int lr = l & 15, lk = l >> 4;

    for (int kc = 0; kc < 10; ++kc) {
        __syncthreads();
        // ---- stage B hi/lo [128][72] from contiguous 16KB weight chunks ----
        {
            const uint4* sh = (const uint4*)(Wy_hi + kc * 8192);
            const uint4* sl = (const uint4*)(Wy_lo + kc * 8192);
            #pragma unroll
            for (int j = 0; j < 4; ++j) {
                uint4 vh = sh[tid + j * 256];
                uint4 vl = sl[tid + j * 256];
                int o = (tid >> 3) + 32 * j, kq = 8 * (tid & 7);
                *(uint4*)(Bh + o * 72 + kq) = vh;
                *(uint4*)(Bl + o * 72 + kq) = vl;
            }
        }
        // ---- stage A hi/lo [64][72] ----
        if (kc < 8) {
            #pragma unroll
            for (int s = 0; s < 2; ++s) {
                int f = s * 256 + tid;
                int t = f >> 3, slot = f & 7;
                uint4 u = *(const uint4*)(hloc + (rowbase + t) * HIDDIM + 32 * kc + 4 * slot);
                unsigned int* Arh = (unsigned int*)Ah + t * 36 + 4 * slot;
                unsigned int* Arl = (unsigned int*)Al + t * 36 + 4 * slot;
                const unsigned int* uu = (const unsigned int*)&u;
                #pragma unroll
                for (int e = 0; e < 4; ++e) {
                    int h = 32 * kc + 4 * slot + e;
                    float2 lp = lampow[t * HIDDIM + h];
                    float2 cr = carryS[h];
                    float hre = bflo(uu[e]) + lp.x * cr.x - lp.y * cr.y;
                    float him = bfhi(uu[e]) + lp.x * cr.y + lp.y * cr.x;
                    unsigned short rh, rl, ih, il;
                    split2(hre, rh, rl); split2(him, ih, il);
                    Arh[e] = ((unsigned int)ih << 16) | rh;
                    Arl[e] = ((unsigned int)il << 16) | rl;
                }
            }
        } else {
            int i0 = (kc - 8) * 64;
            #pragma unroll
            for (int s = 0; s < 4; ++s) {
                int f = s * 256 + tid;
                int t = f >> 4, slot = f & 15;
                float4 v = *(const float4*)(X + (rowbase + t) * INDIM + i0 + 4 * slot);
                unsigned short h0,l0,h1,l1,h2,l2,h3,l3;
                split2(v.x,h0,l0); split2(v.y,h1,l1); split2(v.z,h2,l2); split2(v.w,h3,l3);
                unsigned int* Arh = (unsigned int*)Ah + t * 36 + 2 * slot;
                unsigned int* Arl = (unsigned int*)Al + t * 36 + 2 * slot;
                Arh[0] = ((unsigned int)h1 << 16) | h0;
                Arh[1] = ((unsigned int)h3 << 16) | h2;
                Arl[0] = ((unsigned int)l1 << 16) | l0;
                Arl[1] = ((unsigned int)l3 << 16) | l2;
            }
        }
        __syncthreads();
        // ---- MFMA: 2 k-steps of 32, split-precision (3 products) ----
        #pragma unroll
        for (int ks = 0; ks < 2; ++ks) {
            short8 a0h = *(const short8*)(Ah + (32 * wm + lr) * 72 + 32 * ks + 8 * lk);
            short8 a1h = *(const short8*)(Ah + (32 * wm + 16 + lr) * 72 + 32 * ks + 8 * lk);
            short8 a0l = *(const short8*)(Al + (32 * wm + lr) * 72 + 32 * ks + 8 * lk);
            short8 a1l = *(const short8*)(Al + (32 * wm + 16 + lr) * 72 + 32 * ks + 8 * lk);
            #pragma unroll
            for (int nj = 0; nj < 4; ++nj) {
                short8 bh = *(const short8*)(Bh + (64 * wn + 16 * nj + lr) * 72 + 32 * ks + 8 * lk);
                short8 bl = *(const short8*)(Bl + (64 * wn + 16 * nj + lr) * 72 + 32 * ks + 8 * lk);
                acc[0][nj] = __builtin_amdgcn_mfma_f32_16x16x32_bf16(a0h, bh, acc[0][nj], 0, 0, 0);
                acc[0][nj] = __builtin_amdgcn_mfma_f32_16x16x32_bf16(a0h, bl, acc[0][nj], 0, 0, 0);
                acc[0][nj] = __builtin_amdgcn_mfma_f32_16x16x32_bf16(a0l, bh, acc[0][nj], 0, 0, 0);
                acc[1][nj] = __builtin_amdgcn_mfma_f32_16x16x32_bf16(a1h, bh, acc[1][nj], 0, 0, 0);
                acc[1][nj] = __builtin_amdgcn_mfma_f32_16x16x32_bf16(a1h, bl, acc[1][nj], 0, 0, 0);
                acc[1][nj] = __builtin_amdgcn_mfma_f32_16x16x32_bf16(a1l, bh, acc[1][nj], 0, 0, 0);
            }
        }
    }

    // ---- store Y ----
    float* Yb = Y + rowbase * OUTDIM;
    #pragma unroll
    for (int mi = 0; mi < 2; ++mi)
        #pragma unroll
        for (int nj = 0; nj < 4; ++nj)
            #pragma unroll
            for (int r = 0; r < 4; ++r) {
                int t = 32 * wm + 16 * mi + 4 * lk + r;
                int o = 64 * wn + 16 * nj + lr;
                Yb[(size_t)t * OUTDIM + o] = acc[mi][nj][r];
            }
}

// ---------------------------------------------------------------------------
extern "C" void kernel_launch(void* const* d_in, const int* in_sizes, int n_in,
                              void* d_out, int out_size, void* d_ws, size_t ws_size,
                              hipStream_t stream) {
    const float* X         = (const float*)d_in[0];
    const float* nu_log    = (const float*)d_in[1];
    const float* theta_log = (const float*)d_in[2];
    const float* B_re      = (const float*)d_in[3];
    const float* B_im      = (const float*)d_in[4];
    const float* C_re      = (const float*)d_in[5];
    const float* C_im      = (const float*)d_in[6];
    const float* D         = (const float*)d_in[7];
    float* Y = (float*)d_out;

    // workspace layout (~97.7 MB)
    float2*         BX     = (float2*)d_ws;                                        // 64 MB
    unsigned int*   hloc   = (unsigned int*)((char*)d_ws + (size_t)67108864);      // 32 MB
    float2*         EC     = (float2*)((char*)d_ws + (size_t)100663296);           // 1 MB
    float2*         lampow = (float2*)((char*)d_ws + (size_t)101711872);           // 128 KB
    unsigned short* Wbx_hi = (unsigned short*)((char*)d_ws + (size_t)101842944);   // 128 KB
    unsigned short* Wbx_lo = (unsigned short*)((char*)d_ws + (size_t)101974016);   // 128 KB
    unsigned short* Wy_hi  = (unsigned short*)((char*)d_ws + (size_t)102105088);   // 160 KB
    unsigned short* Wy_lo  = (unsigned short*)((char*)d_ws + (size_t)102268928);   // 160 KB

    hipLaunchKernelGGL(k_prep, dim3(640), dim3(256), 0, stream,
                       nu_log, theta_log, B_re, B_im, C_re, C_im, D,
                       Wbx_hi, Wbx_lo, Wy_hi, Wy_lo, lampow);
    hipLaunchKernelGGL(k_bx, dim3(NBATCH * NCH * 2), dim3(256), 0, stream,
                       X, Wbx_hi, Wbx_lo, BX);
    hipLaunchKernelGGL(k_scan, dim3(NBATCH * NCH), dim3(256), 0, stream,
                       nu_log, theta_log, BX, hloc, EC);
    hipLaunchKernelGGL(k_carry, dim3(NBATCH), dim3(256), 0, stream,
                       nu_log, theta_log, EC);
    hipLaunchKernelGGL(k_y, dim3(NBATCH * NCH), dim3(256), 0, stream,
                       X, hloc, EC, lampow, Wy_hi, Wy_lo, Y);
}